// Round 1
// baseline (1508.760 us; speedup 1.0000x reference)
//
#include <hip/hip_runtime.h>
#include <cstdint>
#include <cstddef>

constexpr int F_IN = 64;
constexpr int HID  = 128;

// ---------------- CSR build ----------------
__global__ void k_hist(const int* __restrict__ ei, int* __restrict__ deg, int E, int n) {
  int i = blockIdx.x * blockDim.x + threadIdx.x;
  int tot = E + n;
  if (i >= tot) return;
  int d = (i < E) ? ei[E + i] : (i - E);   // self-loops appended
  atomicAdd(&deg[d], 1);
}

__global__ void k_scan(const int* __restrict__ deg, int* __restrict__ row_off,
                       int* __restrict__ cursor, int n) {
  // single block, 1024 threads: chunked exclusive scan over n counts
  __shared__ int sums[1024];
  int t = threadIdx.x;
  int chunk = (n + 1023) >> 10;
  int lo = t * chunk, hi = min(lo + chunk, n);
  int s = 0;
  for (int i = lo; i < hi; ++i) s += deg[i];
  sums[t] = s;
  __syncthreads();
  for (int off = 1; off < 1024; off <<= 1) {
    int v = sums[t];
    int add = (t >= off) ? sums[t - off] : 0;
    __syncthreads();
    sums[t] = v + add;
    __syncthreads();
  }
  int run = (t == 0) ? 0 : sums[t - 1];
  for (int i = lo; i < hi; ++i) {
    row_off[i] = run; cursor[i] = run;
    run += deg[i];
  }
  if (t == 1023) row_off[n] = run;
}

__global__ void k_scatter(const int* __restrict__ ei, int* __restrict__ cursor,
                          int* __restrict__ csr_src, int E, int n) {
  int i = blockIdx.x * blockDim.x + threadIdx.x;
  int tot = E + n;
  if (i >= tot) return;
  int s = (i < E) ? ei[i]     : (i - E);
  int d = (i < E) ? ei[E + i] : (i - E);
  int pos = atomicAdd(&cursor[d], 1);
  csr_src[pos] = s;
}

// ---------------- GEMM: [n,K] @ [K,128] -> [n,128] ----------------
template<int K>
__global__ __launch_bounds__(256) void k_gemm(const float* __restrict__ X,
                                              const float* __restrict__ W,
                                              float* __restrict__ Y, int n) {
  __shared__ float Xt[K][16];   // transposed tile: Xt[k][r]
  int t = threadIdx.x;
  int r0 = blockIdx.x * 16;
  for (int i = t; i < 16 * K; i += 256) {
    int r = i / K, k = i - r * K;
    int gr = r0 + r;
    Xt[k][r] = (gr < n) ? X[(size_t)gr * K + k] : 0.f;
  }
  __syncthreads();
  int c  = t & 127;
  int rb = (t >> 7) * 8;
  float acc[8] = {};
  #pragma unroll 4
  for (int k = 0; k < K; ++k) {
    float w = W[k * 128 + c];                      // L1/L2-resident (<=64KB)
    float4 x0 = *(const float4*)&Xt[k][rb];        // broadcast within wave
    float4 x1 = *(const float4*)&Xt[k][rb + 4];
    acc[0] += x0.x * w; acc[1] += x0.y * w; acc[2] += x0.z * w; acc[3] += x0.w * w;
    acc[4] += x1.x * w; acc[5] += x1.y * w; acc[6] += x1.z * w; acc[7] += x1.w * w;
  }
  #pragma unroll
  for (int j = 0; j < 8; ++j) {
    int gr = r0 + rb + j;
    if (gr < n) Y[(size_t)gr * 128 + c] = acc[j];
  }
}

// ---------------- alpha_s / alpha_d ----------------
__global__ void k_alpha(const float* __restrict__ H, const float* __restrict__ a_s,
                        const float* __restrict__ a_d, float* __restrict__ AS,
                        float* __restrict__ AD, int n, int heads, int cph) {
  int i = blockIdx.x * blockDim.x + threadIdx.x;   // (node, head)
  if (i >= n * heads) return;
  int nn = i / heads, h = i - nn * heads;
  const float* row = H + (size_t)nn * HID + h * cph;
  const float* a1 = a_s + h * cph;
  const float* a2 = a_d + h * cph;
  float s1 = 0.f, s2 = 0.f;
  for (int ccc = 0; ccc < cph; ++ccc) { float v = row[ccc]; s1 += v * a1[ccc]; s2 += v * a2[ccc]; }
  AS[i] = s1; AD[i] = s2;
}

// ---------------- GAT aggregation: wave per dst, online softmax ----------------
template<int LOGC>  // channels-per-head = 1<<LOGC (4 for gat1, 7 for gat2/3)
__global__ __launch_bounds__(256) void k_gat_agg(const float* __restrict__ H,
    const int* __restrict__ row_off, const int* __restrict__ csr_src,
    const float* __restrict__ AS, const float* __restrict__ AD,
    const float* __restrict__ bias, float* __restrict__ Y, int n) {
  int wid  = (int)((blockIdx.x * (size_t)blockDim.x + threadIdx.x) >> 6);
  int lane = threadIdx.x & 63;
  if (wid >= n) return;
  const int NH = HID >> LOGC;          // number of heads
  int c = 2 * lane;                    // lane owns channels c, c+1 (same head)
  int h = c >> LOGC;
  float adv = AD[(size_t)wid * NH + h];
  int jb = row_off[wid], je = row_off[wid + 1];
  float m = -1e30f, den = 0.f, a0 = 0.f, a1 = 0.f;
  for (int j = jb; j < je; ++j) {
    int s = csr_src[j];
    float e = AS[(size_t)s * NH + h] + adv;
    e = (e > 0.f) ? e : 0.2f * e;                       // leaky_relu(0.2)
    float2 hv = *(const float2*)(H + (size_t)s * HID + c);
    float nm = fmaxf(m, e);
    float sc = __expf(m - nm);
    float pp = __expf(e - nm);
    den = den * sc + pp;
    a0  = a0  * sc + pp * hv.x;
    a1  = a1  * sc + pp * hv.y;
    m = nm;
  }
  float inv = 1.f / (den + 1e-16f);
  float2 o;
  o.x = a0 * inv + bias[c];
  o.y = a1 * inv + bias[c + 1];
  *(float2*)(Y + (size_t)wid * HID + c) = o;
}

// ---------------- ELU + LayerNorm (+ residual): wave per node ----------------
__global__ __launch_bounds__(256) void k_post(const float* __restrict__ T,
    const float* __restrict__ RES, const float* __restrict__ gamma,
    const float* __restrict__ beta, float* __restrict__ Y, int n, int has_res) {
  int wid  = (int)((blockIdx.x * (size_t)blockDim.x + threadIdx.x) >> 6);
  int lane = threadIdx.x & 63;
  if (wid >= n) return;
  int c = 2 * lane;
  size_t base = (size_t)wid * HID;
  float2 v = *(const float2*)(T + base + c);
  float a0 = v.x > 0.f ? v.x : __expf(v.x) - 1.f;   // ELU
  float a1 = v.y > 0.f ? v.y : __expf(v.y) - 1.f;
  float s1 = a0 + a1, s2 = a0 * a0 + a1 * a1;
  #pragma unroll
  for (int off = 32; off >= 1; off >>= 1) {
    s1 += __shfl_xor(s1, off);
    s2 += __shfl_xor(s2, off);
  }
  float mu  = s1 * (1.f / 128.f);
  float var = s2 * (1.f / 128.f) - mu * mu;
  float rs  = rsqrtf(var + 1e-5f);
  float r0 = 0.f, r1 = 0.f;
  if (has_res) { float2 rv = *(const float2*)(RES + base + c); r0 = rv.x; r1 = rv.y; }
  float2 o;
  o.x = (a0 - mu) * rs * gamma[c]     + beta[c]     + r0;
  o.y = (a1 - mu) * rs * gamma[c + 1] + beta[c + 1] + r1;
  *(float2*)(Y + base + c) = o;
}

// ---------------- global mean pool ----------------
__global__ void k_pool(const float* __restrict__ Hf, const int* __restrict__ batch,
                       float* __restrict__ pool, int* __restrict__ cnt, int n) {
  int i = blockIdx.x * blockDim.x + threadIdx.x;  // (node, channel)
  if (i >= n * HID) return;
  int nn = i >> 7, c = i & 127;
  int g = batch[nn];
  atomicAdd(&pool[g * HID + c], Hf[i]);
  if (c == 0) atomicAdd(&cnt[nn > 0 ? g : g], 1);
}

__global__ void k_divcnt(float* __restrict__ pool, const int* __restrict__ cnt, int G) {
  int i = blockIdx.x * blockDim.x + threadIdx.x;
  if (i >= G * HID) return;
  int g = i >> 7;
  float c = (float)max(cnt[g], 1);
  pool[i] = pool[i] / c;
}

// ---------------- small MLP: [rows,128] @ [128,128] + b (opt ELU) ----------------
__global__ void k_mlp(const float* __restrict__ X, const float* __restrict__ Wt,
                      const float* __restrict__ bb, float* __restrict__ Y,
                      int rows, int do_elu) {
  int i = blockIdx.x * blockDim.x + threadIdx.x;
  if (i >= rows * HID) return;
  int r = i >> 7, c = i & 127;
  const float* xr = X + (size_t)r * HID;
  float acc = bb[c];
  for (int k = 0; k < HID; ++k) acc += xr[k] * Wt[k * HID + c];
  if (do_elu) acc = acc > 0.f ? acc : __expf(acc) - 1.f;
  Y[i] = acc;
}

extern "C" void kernel_launch(void* const* d_in, const int* in_sizes, int n_in,
                              void* d_out, int out_size, void* d_ws, size_t ws_size,
                              hipStream_t stream) {
  const float* x   = (const float*)d_in[0];
  const int*   ei  = (const int*)d_in[1];
  const int*   bat = (const int*)d_in[2];
  const float* W1  = (const float*)d_in[3];
  const float* as1 = (const float*)d_in[4];
  const float* ad1 = (const float*)d_in[5];
  const float* b1  = (const float*)d_in[6];
  const float* W2  = (const float*)d_in[7];
  const float* as2 = (const float*)d_in[8];
  const float* ad2 = (const float*)d_in[9];
  const float* b2  = (const float*)d_in[10];
  const float* W3  = (const float*)d_in[11];
  const float* as3 = (const float*)d_in[12];
  const float* ad3 = (const float*)d_in[13];
  const float* b3  = (const float*)d_in[14];
  const float* g1  = (const float*)d_in[15];
  const float* be1 = (const float*)d_in[16];
  const float* g2  = (const float*)d_in[17];
  const float* be2 = (const float*)d_in[18];
  const float* g3  = (const float*)d_in[19];
  const float* be3 = (const float*)d_in[20];
  const float* lw1 = (const float*)d_in[21];
  const float* lb1 = (const float*)d_in[22];
  const float* lw2 = (const float*)d_in[23];
  const float* lb2 = (const float*)d_in[24];

  int N = in_sizes[0] / F_IN;
  int E = in_sizes[1] / 2;
  int G = out_size / HID;
  int tot = E + N;

  // workspace layout (~170 MB)
  char* p = (char*)d_ws;
  auto alloc = [&](size_t bytes) { char* r = p; p += (bytes + 511) & ~(size_t)511; return r; };
  int*   deg     = (int*)  alloc((size_t)N * 4);
  int*   cursor  = (int*)  alloc((size_t)N * 4);
  int*   row_off = (int*)  alloc((size_t)(N + 1) * 4);
  int*   csr_src = (int*)  alloc((size_t)tot * 4);
  float* AS      = (float*)alloc((size_t)N * 8 * 4);
  float* AD      = (float*)alloc((size_t)N * 8 * 4);
  float* A       = (float*)alloc((size_t)N * HID * 4);
  float* B       = (float*)alloc((size_t)N * HID * 4);
  float* C       = (float*)alloc((size_t)N * HID * 4);
  float* pool    = (float*)alloc((size_t)G * HID * 4);
  int*   cnt     = (int*)  alloc((size_t)G * 4);
  float* t1      = (float*)alloc((size_t)G * HID * 4);

  hipMemsetAsync(deg,  0, (size_t)N * 4, stream);
  hipMemsetAsync(pool, 0, (size_t)G * HID * 4, stream);
  hipMemsetAsync(cnt,  0, (size_t)G * 4, stream);

  int eb = (tot + 255) / 256;
  k_hist   <<<eb, 256, 0, stream>>>(ei, deg, E, N);
  k_scan   <<<1, 1024, 0, stream>>>(deg, row_off, cursor, N);
  k_scatter<<<eb, 256, 0, stream>>>(ei, cursor, csr_src, E, N);

  int gb = (N + 15) / 16;                 // GEMM blocks (16 rows each)
  int nw = (N + 3) / 4;                   // wave-per-node kernels: 4 waves/block

  // ---- layer 1: x[N,64] -> B(h1) -> agg A -> post -> B (features)
  k_gemm<64><<<gb, 256, 0, stream>>>(x, W1, B, N);
  k_alpha<<<(N * 8 + 255) / 256, 256, 0, stream>>>(B, as1, ad1, AS, AD, N, 8, 16);
  k_gat_agg<4><<<nw, 256, 0, stream>>>(B, row_off, csr_src, AS, AD, b1, A, N);
  k_post<<<nw, 256, 0, stream>>>(A, nullptr, g1, be1, B, N, 0);

  // ---- layer 2: B -> A(h2) -> agg C -> post(+B) -> A (features)
  k_gemm<128><<<gb, 256, 0, stream>>>(B, W2, A, N);
  k_alpha<<<(N + 255) / 256, 256, 0, stream>>>(A, as2, ad2, AS, AD, N, 1, 128);
  k_gat_agg<7><<<nw, 256, 0, stream>>>(A, row_off, csr_src, AS, AD, b2, C, N);
  k_post<<<nw, 256, 0, stream>>>(C, B, g2, be2, A, N, 1);

  // ---- layer 3: A -> B(h3) -> agg C -> post(+A) -> B (final features)
  k_gemm<128><<<gb, 256, 0, stream>>>(A, W3, B, N);
  k_alpha<<<(N + 255) / 256, 256, 0, stream>>>(B, as3, ad3, AS, AD, N, 1, 128);
  k_gat_agg<7><<<nw, 256, 0, stream>>>(B, row_off, csr_src, AS, AD, b3, C, N);
  k_post<<<nw, 256, 0, stream>>>(C, A, g3, be3, B, N, 1);

  // ---- pool + MLP head
  k_pool  <<<(N * HID + 255) / 256, 256, 0, stream>>>(B, bat, pool, cnt, N);
  k_divcnt<<<(G * HID + 255) / 256, 256, 0, stream>>>(pool, cnt, G);
  k_mlp   <<<(G * HID + 255) / 256, 256, 0, stream>>>(pool, lw1, lb1, t1, G, 1);
  k_mlp   <<<(G * HID + 255) / 256, 256, 0, stream>>>(t1, lw2, lb2, (float*)d_out, G, 0);
}

// Round 2
// 1074.182 us; speedup vs baseline: 1.4046x; 1.4046x over previous
//
#include <hip/hip_runtime.h>
#include <cstdint>
#include <cstddef>

constexpr int F_IN = 64;
constexpr int HID  = 128;
constexpr int SCB  = 1024;   // scan block size (elements == threads)

// ---------------- CSR build ----------------
__global__ void k_hist(const int* __restrict__ ei, int* __restrict__ deg, int E, int n) {
  int i = blockIdx.x * blockDim.x + threadIdx.x;
  int tot = E + n;
  if (i >= tot) return;
  int d = (i < E) ? ei[E + i] : (i - E);   // self-loops appended
  atomicAdd(&deg[d], 1);
}

// block-local exclusive scan; per-block totals to bsum
__global__ __launch_bounds__(SCB) void k_scan1(const int* __restrict__ deg,
                                               int* __restrict__ part,
                                               int* __restrict__ bsum, int n) {
  __shared__ int tmp[SCB];
  int t = threadIdx.x;
  int i = blockIdx.x * SCB + t;
  int v = (i < n) ? deg[i] : 0;
  tmp[t] = v;
  __syncthreads();
  #pragma unroll
  for (int off = 1; off < SCB; off <<= 1) {
    int x = tmp[t];
    int add = (t >= off) ? tmp[t - off] : 0;
    __syncthreads();
    tmp[t] = x + add;
    __syncthreads();
  }
  if (i < n) part[i] = tmp[t] - v;            // exclusive
  if (t == SCB - 1) bsum[blockIdx.x] = tmp[t]; // inclusive total
}

// scan the (<=1024) block sums in one block
__global__ __launch_bounds__(SCB) void k_scan2(int* __restrict__ bsum, int nb) {
  __shared__ int tmp[SCB];
  int t = threadIdx.x;
  int v = (t < nb) ? bsum[t] : 0;
  tmp[t] = v;
  __syncthreads();
  #pragma unroll
  for (int off = 1; off < SCB; off <<= 1) {
    int x = tmp[t];
    int add = (t >= off) ? tmp[t - off] : 0;
    __syncthreads();
    tmp[t] = x + add;
    __syncthreads();
  }
  if (t < nb) bsum[t] = tmp[t] - v;           // exclusive block offsets
}

// add block offsets; emit row_off + cursor; write row_off[n]=tot
__global__ void k_scan3(int* __restrict__ row_off, int* __restrict__ cursor,
                        const int* __restrict__ part, const int* __restrict__ bsum,
                        int n, int tot) {
  int i = blockIdx.x * blockDim.x + threadIdx.x;
  if (i == 0) row_off[n] = tot;
  if (i >= n) return;
  int r = part[i] + bsum[i >> 10];
  row_off[i] = r;
  cursor[i]  = r;
}

__global__ void k_scatter(const int* __restrict__ ei, int* __restrict__ cursor,
                          int* __restrict__ csr_src, int E, int n) {
  int i = blockIdx.x * blockDim.x + threadIdx.x;
  int tot = E + n;
  if (i >= tot) return;
  int s = (i < E) ? ei[i]     : (i - E);
  int d = (i < E) ? ei[E + i] : (i - E);
  int pos = atomicAdd(&cursor[d], 1);
  csr_src[pos] = s;
}

// ---------------- GEMM: [n,K] @ [K,128] -> [n,128] ----------------
template<int K>
__global__ __launch_bounds__(256) void k_gemm(const float* __restrict__ X,
                                              const float* __restrict__ W,
                                              float* __restrict__ Y, int n) {
  __shared__ float Xt[K][16];   // transposed tile: Xt[k][r]
  int t = threadIdx.x;
  int r0 = blockIdx.x * 16;
  for (int i = t; i < 16 * K; i += 256) {
    int r = i / K, k = i - r * K;
    int gr = r0 + r;
    Xt[k][r] = (gr < n) ? X[(size_t)gr * K + k] : 0.f;
  }
  __syncthreads();
  int c  = t & 127;
  int rb = (t >> 7) * 8;
  float acc[8] = {};
  #pragma unroll 4
  for (int k = 0; k < K; ++k) {
    float w = W[k * 128 + c];                      // L1/L2-resident (<=64KB)
    float4 x0 = *(const float4*)&Xt[k][rb];        // broadcast within wave
    float4 x1 = *(const float4*)&Xt[k][rb + 4];
    acc[0] += x0.x * w; acc[1] += x0.y * w; acc[2] += x0.z * w; acc[3] += x0.w * w;
    acc[4] += x1.x * w; acc[5] += x1.y * w; acc[6] += x1.z * w; acc[7] += x1.w * w;
  }
  #pragma unroll
  for (int j = 0; j < 8; ++j) {
    int gr = r0 + rb + j;
    if (gr < n) Y[(size_t)gr * 128 + c] = acc[j];
  }
}

// ---------------- alpha_s / alpha_d ----------------
__global__ void k_alpha(const float* __restrict__ H, const float* __restrict__ a_s,
                        const float* __restrict__ a_d, float* __restrict__ AS,
                        float* __restrict__ AD, int n, int heads, int cph) {
  int i = blockIdx.x * blockDim.x + threadIdx.x;   // (node, head)
  if (i >= n * heads) return;
  int nn = i / heads, h = i - nn * heads;
  const float* row = H + (size_t)nn * HID + h * cph;
  const float* a1 = a_s + h * cph;
  const float* a2 = a_d + h * cph;
  float s1 = 0.f, s2 = 0.f;
  for (int ccc = 0; ccc < cph; ++ccc) { float v = row[ccc]; s1 += v * a1[ccc]; s2 += v * a2[ccc]; }
  AS[i] = s1; AD[i] = s2;
}

// ---------------- GAT aggregation: wave per dst, online softmax ----------------
template<int LOGC>  // channels-per-head = 1<<LOGC (4 for gat1, 7 for gat2/3)
__global__ __launch_bounds__(256) void k_gat_agg(const float* __restrict__ H,
    const int* __restrict__ row_off, const int* __restrict__ csr_src,
    const float* __restrict__ AS, const float* __restrict__ AD,
    const float* __restrict__ bias, float* __restrict__ Y, int n) {
  int wid  = (int)((blockIdx.x * (size_t)blockDim.x + threadIdx.x) >> 6);
  int lane = threadIdx.x & 63;
  if (wid >= n) return;
  const int NH = HID >> LOGC;          // number of heads
  int c = 2 * lane;                    // lane owns channels c, c+1 (same head)
  int h = c >> LOGC;
  float adv = AD[(size_t)wid * NH + h];
  int jb = row_off[wid], je = row_off[wid + 1];
  float m = -1e30f, den = 0.f, a0 = 0.f, a1 = 0.f;
  int s_next = (jb < je) ? csr_src[jb] : 0;
  for (int j = jb; j < je; ++j) {
    int s = s_next;
    if (j + 1 < je) s_next = csr_src[j + 1];      // prefetch index
    float e = AS[(size_t)s * NH + h] + adv;
    e = (e > 0.f) ? e : 0.2f * e;                 // leaky_relu(0.2)
    float2 hv = *(const float2*)(H + (size_t)s * HID + c);
    float nm = fmaxf(m, e);
    float sc = __expf(m - nm);
    float pp = __expf(e - nm);
    den = den * sc + pp;
    a0  = a0  * sc + pp * hv.x;
    a1  = a1  * sc + pp * hv.y;
    m = nm;
  }
  float inv = 1.f / (den + 1e-16f);
  float2 o;
  o.x = a0 * inv + bias[c];
  o.y = a1 * inv + bias[c + 1];
  *(float2*)(Y + (size_t)wid * HID + c) = o;
}

// ---------------- ELU + LayerNorm (+ residual): wave per node ----------------
__global__ __launch_bounds__(256) void k_post(const float* __restrict__ T,
    const float* __restrict__ RES, const float* __restrict__ gamma,
    const float* __restrict__ beta, float* __restrict__ Y, int n, int has_res) {
  int wid  = (int)((blockIdx.x * (size_t)blockDim.x + threadIdx.x) >> 6);
  int lane = threadIdx.x & 63;
  if (wid >= n) return;
  int c = 2 * lane;
  size_t base = (size_t)wid * HID;
  float2 v = *(const float2*)(T + base + c);
  float a0 = v.x > 0.f ? v.x : __expf(v.x) - 1.f;   // ELU
  float a1 = v.y > 0.f ? v.y : __expf(v.y) - 1.f;
  float s1 = a0 + a1, s2 = a0 * a0 + a1 * a1;
  #pragma unroll
  for (int off = 32; off >= 1; off >>= 1) {
    s1 += __shfl_xor(s1, off);
    s2 += __shfl_xor(s2, off);
  }
  float mu  = s1 * (1.f / 128.f);
  float var = s2 * (1.f / 128.f) - mu * mu;
  float rs  = rsqrtf(var + 1e-5f);
  float r0 = 0.f, r1 = 0.f;
  if (has_res) { float2 rv = *(const float2*)(RES + base + c); r0 = rv.x; r1 = rv.y; }
  float2 o;
  o.x = (a0 - mu) * rs * gamma[c]     + beta[c]     + r0;
  o.y = (a1 - mu) * rs * gamma[c + 1] + beta[c + 1] + r1;
  *(float2*)(Y + base + c) = o;
}

// ---------------- global mean pool: wave per graph (batch is sorted) ----------------
__global__ __launch_bounds__(256) void k_pool_seg(const float* __restrict__ Hf,
    const int* __restrict__ batch, float* __restrict__ pool, int n, int G) {
  int wid  = (int)((blockIdx.x * (size_t)blockDim.x + threadIdx.x) >> 6);
  int lane = threadIdx.x & 63;
  if (wid >= G) return;
  // lower_bound(batch, wid) and lower_bound(batch, wid+1)
  int lo = 0, hi = n;
  while (lo < hi) { int mid = (lo + hi) >> 1; if (batch[mid] < wid) lo = mid + 1; else hi = mid; }
  int start = lo;
  hi = n;
  while (lo < hi) { int mid = (lo + hi) >> 1; if (batch[mid] < wid + 1) lo = mid + 1; else hi = mid; }
  int end = lo;
  int c = 2 * lane;
  float s0 = 0.f, s1 = 0.f;
  for (int i = start; i < end; ++i) {
    float2 v = *(const float2*)(Hf + (size_t)i * HID + c);
    s0 += v.x; s1 += v.y;
  }
  float inv = 1.f / (float)max(end - start, 1);
  pool[(size_t)wid * HID + c]     = s0 * inv;
  pool[(size_t)wid * HID + c + 1] = s1 * inv;
}

// ---------------- small MLP: [rows,128] @ [128,128] + b (opt ELU) ----------------
__global__ void k_mlp(const float* __restrict__ X, const float* __restrict__ Wt,
                      const float* __restrict__ bb, float* __restrict__ Y,
                      int rows, int do_elu) {
  int i = blockIdx.x * blockDim.x + threadIdx.x;
  if (i >= rows * HID) return;
  int r = i >> 7, c = i & 127;
  const float* xr = X + (size_t)r * HID;
  float acc = bb[c];
  for (int k = 0; k < HID; ++k) acc += xr[k] * Wt[k * HID + c];
  if (do_elu) acc = acc > 0.f ? acc : __expf(acc) - 1.f;
  Y[i] = acc;
}

extern "C" void kernel_launch(void* const* d_in, const int* in_sizes, int n_in,
                              void* d_out, int out_size, void* d_ws, size_t ws_size,
                              hipStream_t stream) {
  const float* x   = (const float*)d_in[0];
  const int*   ei  = (const int*)d_in[1];
  const int*   bat = (const int*)d_in[2];
  const float* W1  = (const float*)d_in[3];
  const float* as1 = (const float*)d_in[4];
  const float* ad1 = (const float*)d_in[5];
  const float* b1  = (const float*)d_in[6];
  const float* W2  = (const float*)d_in[7];
  const float* as2 = (const float*)d_in[8];
  const float* ad2 = (const float*)d_in[9];
  const float* b2  = (const float*)d_in[10];
  const float* W3  = (const float*)d_in[11];
  const float* as3 = (const float*)d_in[12];
  const float* ad3 = (const float*)d_in[13];
  const float* b3  = (const float*)d_in[14];
  const float* g1  = (const float*)d_in[15];
  const float* be1 = (const float*)d_in[16];
  const float* g2  = (const float*)d_in[17];
  const float* be2 = (const float*)d_in[18];
  const float* g3  = (const float*)d_in[19];
  const float* be3 = (const float*)d_in[20];
  const float* lw1 = (const float*)d_in[21];
  const float* lb1 = (const float*)d_in[22];
  const float* lw2 = (const float*)d_in[23];
  const float* lb2 = (const float*)d_in[24];

  int N = in_sizes[0] / F_IN;
  int E = in_sizes[1] / 2;
  int G = out_size / HID;
  int tot = E + N;
  int nb  = (N + SCB - 1) / SCB;   // scan blocks (<=1024)

  // workspace layout
  char* p = (char*)d_ws;
  auto alloc = [&](size_t bytes) { char* r = p; p += (bytes + 511) & ~(size_t)511; return r; };
  int*   deg     = (int*)  alloc((size_t)N * 4);
  int*   part    = (int*)  alloc((size_t)N * 4);
  int*   bsum    = (int*)  alloc((size_t)SCB * 4);
  int*   cursor  = (int*)  alloc((size_t)N * 4);
  int*   row_off = (int*)  alloc((size_t)(N + 1) * 4);
  int*   csr_src = (int*)  alloc((size_t)tot * 4);
  float* AS      = (float*)alloc((size_t)N * 8 * 4);
  float* AD      = (float*)alloc((size_t)N * 8 * 4);
  float* A       = (float*)alloc((size_t)N * HID * 4);
  float* B       = (float*)alloc((size_t)N * HID * 4);
  float* C       = (float*)alloc((size_t)N * HID * 4);
  float* pool    = (float*)alloc((size_t)G * HID * 4);
  float* t1      = (float*)alloc((size_t)G * HID * 4);

  hipMemsetAsync(deg, 0, (size_t)N * 4, stream);

  int eb = (tot + 255) / 256;
  k_hist <<<eb, 256, 0, stream>>>(ei, deg, E, N);
  k_scan1<<<nb, SCB, 0, stream>>>(deg, part, bsum, N);
  k_scan2<<<1, SCB, 0, stream>>>(bsum, nb);
  k_scan3<<<(N + 255) / 256, 256, 0, stream>>>(row_off, cursor, part, bsum, N, tot);
  k_scatter<<<eb, 256, 0, stream>>>(ei, cursor, csr_src, E, N);

  int gb = (N + 15) / 16;                 // GEMM blocks (16 rows each)
  int nw = (N + 3) / 4;                   // wave-per-node kernels: 4 waves/block

  // ---- layer 1: x[N,64] -> B(h1) -> agg A -> post -> B (features)
  k_gemm<64><<<gb, 256, 0, stream>>>(x, W1, B, N);
  k_alpha<<<(N * 8 + 255) / 256, 256, 0, stream>>>(B, as1, ad1, AS, AD, N, 8, 16);
  k_gat_agg<4><<<nw, 256, 0, stream>>>(B, row_off, csr_src, AS, AD, b1, A, N);
  k_post<<<nw, 256, 0, stream>>>(A, nullptr, g1, be1, B, N, 0);

  // ---- layer 2: B -> A(h2) -> agg C -> post(+B) -> A (features)
  k_gemm<128><<<gb, 256, 0, stream>>>(B, W2, A, N);
  k_alpha<<<(N + 255) / 256, 256, 0, stream>>>(A, as2, ad2, AS, AD, N, 1, 128);
  k_gat_agg<7><<<nw, 256, 0, stream>>>(A, row_off, csr_src, AS, AD, b2, C, N);
  k_post<<<nw, 256, 0, stream>>>(C, B, g2, be2, A, N, 1);

  // ---- layer 3: A -> B(h3) -> agg C -> post(+A) -> B (final features)
  k_gemm<128><<<gb, 256, 0, stream>>>(A, W3, B, N);
  k_alpha<<<(N + 255) / 256, 256, 0, stream>>>(B, as3, ad3, AS, AD, N, 1, 128);
  k_gat_agg<7><<<nw, 256, 0, stream>>>(B, row_off, csr_src, AS, AD, b3, C, N);
  k_post<<<nw, 256, 0, stream>>>(C, A, g3, be3, B, N, 1);

  // ---- pool + MLP head
  k_pool_seg<<<(G + 3) / 4, 256, 0, stream>>>(B, bat, pool, N, G);
  k_mlp<<<(G * HID + 255) / 256, 256, 0, stream>>>(pool, lw1, lb1, t1, G, 1);
  k_mlp<<<(G * HID + 255) / 256, 256, 0, stream>>>(t1, lw2, lb2, (float*)d_out, G, 0);
}

// Round 3
// 859.215 us; speedup vs baseline: 1.7560x; 1.2502x over previous
//
#include <hip/hip_runtime.h>
#include <hip/hip_bf16.h>
#include <cstdint>
#include <cstddef>

constexpr int F_IN = 64;
constexpr int HID  = 128;
constexpr int SCB  = 1024;   // scan block size (elements == threads)

__device__ __forceinline__ float bf2f(unsigned short u) {
  return __uint_as_float((unsigned)u << 16);
}

// ---------------- CSR build ----------------
__global__ void k_hist(const int* __restrict__ ei, int* __restrict__ deg, int E, int n) {
  int i = blockIdx.x * blockDim.x + threadIdx.x;
  int tot = E + n;
  if (i >= tot) return;
  int d = (i < E) ? ei[E + i] : (i - E);   // self-loops appended
  atomicAdd(&deg[d], 1);
}

__global__ __launch_bounds__(SCB) void k_scan1(const int* __restrict__ deg,
                                               int* __restrict__ part,
                                               int* __restrict__ bsum, int n) {
  __shared__ int tmp[SCB];
  int t = threadIdx.x;
  int i = blockIdx.x * SCB + t;
  int v = (i < n) ? deg[i] : 0;
  tmp[t] = v;
  __syncthreads();
  #pragma unroll
  for (int off = 1; off < SCB; off <<= 1) {
    int x = tmp[t];
    int add = (t >= off) ? tmp[t - off] : 0;
    __syncthreads();
    tmp[t] = x + add;
    __syncthreads();
  }
  if (i < n) part[i] = tmp[t] - v;            // exclusive
  if (t == SCB - 1) bsum[blockIdx.x] = tmp[t]; // inclusive total
}

__global__ __launch_bounds__(SCB) void k_scan2(int* __restrict__ bsum, int nb) {
  __shared__ int tmp[SCB];
  int t = threadIdx.x;
  int v = (t < nb) ? bsum[t] : 0;
  tmp[t] = v;
  __syncthreads();
  #pragma unroll
  for (int off = 1; off < SCB; off <<= 1) {
    int x = tmp[t];
    int add = (t >= off) ? tmp[t - off] : 0;
    __syncthreads();
    tmp[t] = x + add;
    __syncthreads();
  }
  if (t < nb) bsum[t] = tmp[t] - v;           // exclusive block offsets
}

__global__ void k_scan3(int* __restrict__ row_off, int* __restrict__ cursor,
                        const int* __restrict__ part, const int* __restrict__ bsum,
                        int n, int tot) {
  int i = blockIdx.x * blockDim.x + threadIdx.x;
  if (i == 0) row_off[n] = tot;
  if (i >= n) return;
  int r = part[i] + bsum[i >> 10];
  row_off[i] = r;
  cursor[i]  = r;
}

__global__ void k_scatter(const int* __restrict__ ei, int* __restrict__ cursor,
                          int* __restrict__ csr_src, int E, int n) {
  int i = blockIdx.x * blockDim.x + threadIdx.x;
  int tot = E + n;
  if (i >= tot) return;
  int s = (i < E) ? ei[i]     : (i - E);
  int d = (i < E) ? ei[E + i] : (i - E);
  int pos = atomicAdd(&cursor[d], 1);
  csr_src[pos] = s;
}

// ---------------- GEMM: [n,K] fp32 @ [K,128] fp32 -> [n,128] bf16 ----------------
template<int K>
__global__ __launch_bounds__(256) void k_gemm(const float* __restrict__ X,
                                              const float* __restrict__ W,
                                              __hip_bfloat16* __restrict__ Y, int n) {
  __shared__ float Xt[K][16];   // transposed tile: Xt[k][r]
  int t = threadIdx.x;
  int r0 = blockIdx.x * 16;
  for (int i = t; i < 16 * K; i += 256) {
    int r = i / K, k = i - r * K;
    int gr = r0 + r;
    Xt[k][r] = (gr < n) ? X[(size_t)gr * K + k] : 0.f;
  }
  __syncthreads();
  int c  = t & 127;
  int rb = (t >> 7) * 8;
  float acc[8] = {};
  #pragma unroll 4
  for (int k = 0; k < K; ++k) {
    float w = W[k * 128 + c];
    float4 x0 = *(const float4*)&Xt[k][rb];
    float4 x1 = *(const float4*)&Xt[k][rb + 4];
    acc[0] += x0.x * w; acc[1] += x0.y * w; acc[2] += x0.z * w; acc[3] += x0.w * w;
    acc[4] += x1.x * w; acc[5] += x1.y * w; acc[6] += x1.z * w; acc[7] += x1.w * w;
  }
  #pragma unroll
  for (int j = 0; j < 8; ++j) {
    int gr = r0 + rb + j;
    if (gr < n) Y[(size_t)gr * 128 + c] = __float2bfloat16(acc[j]);
  }
}

// ---------------- alpha: wave per node, coalesced bf16 reads ----------------
template<int LOGC>  // SEG = lanes per head = (1<<LOGC)/2
__global__ __launch_bounds__(256) void k_alpha(const __hip_bfloat16* __restrict__ H,
    const float* __restrict__ a_s, const float* __restrict__ a_d,
    float* __restrict__ AS, float* __restrict__ AD, int n) {
  int wid  = (int)((blockIdx.x * (size_t)blockDim.x + threadIdx.x) >> 6);
  int lane = threadIdx.x & 63;
  if (wid >= n) return;
  constexpr int SEG = 1 << (LOGC - 1);
  constexpr int NH  = HID >> LOGC;
  int c = 2 * lane;
  ushort2 u = *(const ushort2*)((const unsigned short*)H + (size_t)wid * HID + c);
  float h0 = bf2f(u.x), h1 = bf2f(u.y);
  float s1 = h0 * a_s[c] + h1 * a_s[c + 1];
  float s2 = h0 * a_d[c] + h1 * a_d[c + 1];
  #pragma unroll
  for (int off = 1; off < SEG; off <<= 1) {
    s1 += __shfl_xor(s1, off);
    s2 += __shfl_xor(s2, off);
  }
  if ((lane & (SEG - 1)) == 0) {
    int h = lane / SEG;
    AS[(size_t)wid * NH + h] = s1;
    AD[(size_t)wid * NH + h] = s2;
  }
}

// ------- GAT aggregation + bias + ELU + LayerNorm + residual (fused) -------
template<int LOGC>  // channels-per-head = 1<<LOGC
__global__ __launch_bounds__(256) void k_agg_post(const __hip_bfloat16* __restrict__ H,
    const int* __restrict__ row_off, const int* __restrict__ csr_src,
    const float* __restrict__ AS, const float* __restrict__ AD,
    const float* __restrict__ bias, const float* __restrict__ RES,
    const float* __restrict__ gamma, const float* __restrict__ beta,
    float* __restrict__ Y, int n, int has_res) {
  int wid  = (int)((blockIdx.x * (size_t)blockDim.x + threadIdx.x) >> 6);
  int lane = threadIdx.x & 63;
  if (wid >= n) return;
  const int NH = HID >> LOGC;
  int c = 2 * lane;                    // lane owns channels c, c+1 (same head)
  int h = c >> LOGC;
  float adv = AD[(size_t)wid * NH + h];
  int jb = row_off[wid], je = row_off[wid + 1];
  float m = -1e30f, den = 0.f, a0 = 0.f, a1 = 0.f;
  int s_next = (jb < je) ? csr_src[jb] : 0;
  const unsigned short* Hu = (const unsigned short*)H;
  for (int j = jb; j < je; ++j) {
    int s = s_next;
    if (j + 1 < je) s_next = csr_src[j + 1];      // prefetch index
    float e = AS[(size_t)s * NH + h] + adv;
    e = (e > 0.f) ? e : 0.2f * e;                 // leaky_relu(0.2)
    ushort2 u = *(const ushort2*)(Hu + (size_t)s * HID + c);
    float nm = fmaxf(m, e);
    float sc = __expf(m - nm);
    float pp = __expf(e - nm);
    den = den * sc + pp;
    a0  = a0  * sc + pp * bf2f(u.x);
    a1  = a1  * sc + pp * bf2f(u.y);
    m = nm;
  }
  float inv = 1.f / (den + 1e-16f);
  float t0 = a0 * inv + bias[c];
  float t1 = a1 * inv + bias[c + 1];
  // ELU
  float e0 = t0 > 0.f ? t0 : __expf(t0) - 1.f;
  float e1 = t1 > 0.f ? t1 : __expf(t1) - 1.f;
  // LayerNorm over the 128 channels held by this wave
  float s1 = e0 + e1, s2 = e0 * e0 + e1 * e1;
  #pragma unroll
  for (int off = 32; off >= 1; off >>= 1) {
    s1 += __shfl_xor(s1, off);
    s2 += __shfl_xor(s2, off);
  }
  float mu  = s1 * (1.f / 128.f);
  float var = s2 * (1.f / 128.f) - mu * mu;
  float rs  = rsqrtf(var + 1e-5f);
  size_t base = (size_t)wid * HID;
  float r0 = 0.f, r1 = 0.f;
  if (has_res) { float2 rv = *(const float2*)(RES + base + c); r0 = rv.x; r1 = rv.y; }
  float2 o;
  o.x = (e0 - mu) * rs * gamma[c]     + beta[c]     + r0;
  o.y = (e1 - mu) * rs * gamma[c + 1] + beta[c + 1] + r1;
  *(float2*)(Y + base + c) = o;
}

// ---------------- global mean pool: wave per graph (batch is sorted) ----------------
__global__ __launch_bounds__(256) void k_pool_seg(const float* __restrict__ Hf,
    const int* __restrict__ batch, float* __restrict__ pool, int n, int G) {
  int wid  = (int)((blockIdx.x * (size_t)blockDim.x + threadIdx.x) >> 6);
  int lane = threadIdx.x & 63;
  if (wid >= G) return;
  int lo = 0, hi = n;
  while (lo < hi) { int mid = (lo + hi) >> 1; if (batch[mid] < wid) lo = mid + 1; else hi = mid; }
  int start = lo;
  hi = n;
  while (lo < hi) { int mid = (lo + hi) >> 1; if (batch[mid] < wid + 1) lo = mid + 1; else hi = mid; }
  int end = lo;
  int c = 2 * lane;
  float s0 = 0.f, s1 = 0.f;
  for (int i = start; i < end; ++i) {
    float2 v = *(const float2*)(Hf + (size_t)i * HID + c);
    s0 += v.x; s1 += v.y;
  }
  float inv = 1.f / (float)max(end - start, 1);
  pool[(size_t)wid * HID + c]     = s0 * inv;
  pool[(size_t)wid * HID + c + 1] = s1 * inv;
}

// ---------------- small MLP: [rows,128] @ [128,128] + b (opt ELU) ----------------
__global__ void k_mlp(const float* __restrict__ X, const float* __restrict__ Wt,
                      const float* __restrict__ bb, float* __restrict__ Y,
                      int rows, int do_elu) {
  int i = blockIdx.x * blockDim.x + threadIdx.x;
  if (i >= rows * HID) return;
  int r = i >> 7, c = i & 127;
  const float* xr = X + (size_t)r * HID;
  float acc = bb[c];
  for (int k = 0; k < HID; ++k) acc += xr[k] * Wt[k * HID + c];
  if (do_elu) acc = acc > 0.f ? acc : __expf(acc) - 1.f;
  Y[i] = acc;
}

extern "C" void kernel_launch(void* const* d_in, const int* in_sizes, int n_in,
                              void* d_out, int out_size, void* d_ws, size_t ws_size,
                              hipStream_t stream) {
  const float* x   = (const float*)d_in[0];
  const int*   ei  = (const int*)d_in[1];
  const int*   bat = (const int*)d_in[2];
  const float* W1  = (const float*)d_in[3];
  const float* as1 = (const float*)d_in[4];
  const float* ad1 = (const float*)d_in[5];
  const float* b1  = (const float*)d_in[6];
  const float* W2  = (const float*)d_in[7];
  const float* as2 = (const float*)d_in[8];
  const float* ad2 = (const float*)d_in[9];
  const float* b2  = (const float*)d_in[10];
  const float* W3  = (const float*)d_in[11];
  const float* as3 = (const float*)d_in[12];
  const float* ad3 = (const float*)d_in[13];
  const float* b3  = (const float*)d_in[14];
  const float* g1  = (const float*)d_in[15];
  const float* be1 = (const float*)d_in[16];
  const float* g2  = (const float*)d_in[17];
  const float* be2 = (const float*)d_in[18];
  const float* g3  = (const float*)d_in[19];
  const float* be3 = (const float*)d_in[20];
  const float* lw1 = (const float*)d_in[21];
  const float* lb1 = (const float*)d_in[22];
  const float* lw2 = (const float*)d_in[23];
  const float* lb2 = (const float*)d_in[24];

  int N = in_sizes[0] / F_IN;
  int E = in_sizes[1] / 2;
  int G = out_size / HID;
  int tot = E + N;
  int nb  = (N + SCB - 1) / SCB;

  char* p = (char*)d_ws;
  auto alloc = [&](size_t bytes) { char* r = p; p += (bytes + 511) & ~(size_t)511; return r; };
  int*   deg     = (int*)  alloc((size_t)N * 4);
  int*   part    = (int*)  alloc((size_t)N * 4);
  int*   bsum    = (int*)  alloc((size_t)SCB * 4);
  int*   cursor  = (int*)  alloc((size_t)N * 4);
  int*   row_off = (int*)  alloc((size_t)(N + 1) * 4);
  int*   csr_src = (int*)  alloc((size_t)tot * 4);
  float* AS      = (float*)alloc((size_t)N * 8 * 4);
  float* AD      = (float*)alloc((size_t)N * 8 * 4);
  __hip_bfloat16* Hb = (__hip_bfloat16*)alloc((size_t)N * HID * 2);
  float* F0      = (float*)alloc((size_t)N * HID * 4);
  float* F1      = (float*)alloc((size_t)N * HID * 4);
  float* pool    = (float*)alloc((size_t)G * HID * 4);
  float* t1      = (float*)alloc((size_t)G * HID * 4);

  hipMemsetAsync(deg, 0, (size_t)N * 4, stream);

  int eb = (tot + 255) / 256;
  k_hist <<<eb, 256, 0, stream>>>(ei, deg, E, N);
  k_scan1<<<nb, SCB, 0, stream>>>(deg, part, bsum, N);
  k_scan2<<<1, SCB, 0, stream>>>(bsum, nb);
  k_scan3<<<(N + 255) / 256, 256, 0, stream>>>(row_off, cursor, part, bsum, N, tot);
  k_scatter<<<eb, 256, 0, stream>>>(ei, cursor, csr_src, E, N);

  int gb = (N + 15) / 16;                 // GEMM blocks (16 rows each)
  int nw = (N + 3) / 4;                   // wave-per-node kernels: 4 waves/block

  // ---- layer 1: x[N,64] -> Hb -> agg+post -> F0
  k_gemm<64><<<gb, 256, 0, stream>>>(x, W1, Hb, N);
  k_alpha<4><<<nw, 256, 0, stream>>>(Hb, as1, ad1, AS, AD, N);
  k_agg_post<4><<<nw, 256, 0, stream>>>(Hb, row_off, csr_src, AS, AD, b1,
                                        nullptr, g1, be1, F0, N, 0);

  // ---- layer 2: F0 -> Hb -> agg+post(+F0) -> F1
  k_gemm<128><<<gb, 256, 0, stream>>>(F0, W2, Hb, N);
  k_alpha<7><<<nw, 256, 0, stream>>>(Hb, as2, ad2, AS, AD, N);
  k_agg_post<7><<<nw, 256, 0, stream>>>(Hb, row_off, csr_src, AS, AD, b2,
                                        F0, g2, be2, F1, N, 1);

  // ---- layer 3: F1 -> Hb -> agg+post(+F1) -> F0
  k_gemm<128><<<gb, 256, 0, stream>>>(F1, W3, Hb, N);
  k_alpha<7><<<nw, 256, 0, stream>>>(Hb, as3, ad3, AS, AD, N);
  k_agg_post<7><<<nw, 256, 0, stream>>>(Hb, row_off, csr_src, AS, AD, b3,
                                        F1, g3, be3, F0, N, 1);

  // ---- pool + MLP head
  k_pool_seg<<<(G + 3) / 4, 256, 0, stream>>>(F0, bat, pool, N, G);
  k_mlp<<<(G * HID + 255) / 256, 256, 0, stream>>>(pool, lw1, lb1, t1, G, 1);
  k_mlp<<<(G * HID + 255) / 256, 256, 0, stream>>>(t1, lw2, lb2, (float*)d_out, G, 0);
}